// Round 15
// baseline (155.686 us; speedup 1.0000x reference)
//
#include <hip/hip_runtime.h>
#include <hip/hip_fp16.h>

// GLOBE_61864708931733 — R15: software-pipeline frag loads one layer ahead.
// R14 post-mortem: C==B register dataflow killed LDS conflicts (5.1M->0.66M)
// but dur stayed ~74us -> LDS wasn't the wall. R6/R11/R14 all 68-75us at
// VALUBusy 52-60% => ~45% issue idle on latency. Unattacked: each layer's 8
// frag loads (L2-hit ~200-400cy) issue right before their MFMAs = 4-5 stall
// points/chunk. R15: prefetch L1+L2 frags + biases at chunk top (covered by
// feature calc), L3's during L1, Wout's during L2. Supply is 4 waves/SIMD
// (grid-fixed) so regs <=128 are free; est ~115. All else identical to R14.

#define N_T 2048
#define N_S 512
#define BLK 128
#define SCALE 2.885390081777927f   // 2*log2(e)

// d_ws: 4 copies, stride 5888 floats (23552 B):
//   units 0..21: f16x4-frag pairs, unit u = [64 lanes][16 B]
//     u 0..1:  W1 (unit0: mt0 lo / mt1 hi; unit1: mt2/mt3), kt=0 only
//     u 2..9:  W2: unit 2+mt*2+kp = frags (mt, kt=2kp) lo / (mt, 2kp+1) hi
//     u 10..17: W3 same
//     u 18..19: Wout hi | u 20..21: Wout lo
//   floats 5632..5823: scaled biases [3][64]
#define CPY_F 5888     // floats per copy
#define CPY_U 1472     // 16B units per copy

typedef _Float16 f16;
typedef _Float16 f16x4 __attribute__((ext_vector_type(4)));
typedef float f32x4 __attribute__((ext_vector_type(4)));
typedef unsigned short u16;
typedef unsigned int u32;

__device__ __forceinline__ float tanh_s(float x) {
    // x is already SCALE*y; tanh(y) = 1 - 2/(exp2(x)+1). Saturates exactly.
    float e = __builtin_amdgcn_exp2f(x);
    return fmaf(-2.0f, __builtin_amdgcn_rcpf(e + 1.0f), 1.0f);
}

__device__ __forceinline__ f32x4 mfma16(f16x4 a, f16x4 b, f32x4 c) {
    return __builtin_amdgcn_mfma_f32_16x16x16f16(a, b, c, 0, 0, 0);
}

__device__ __forceinline__ u32 pkrtz(float a, float b) {
    return __builtin_bit_cast(u32, __builtin_amdgcn_cvt_pkrtz(a, b));
}

__device__ __forceinline__ f16x4 lo4(uint4 g) {
    uint2 p; p.x = g.x; p.y = g.y;
    return __builtin_bit_cast(f16x4, p);
}
__device__ __forceinline__ f16x4 hi4(uint4 g) {
    uint2 p; p.x = g.z; p.y = g.w;
    return __builtin_bit_cast(f16x4, p);
}

// tanh + pack a C f32x4 into the next layer's B frag (C==B layout identity).
__device__ __forceinline__ f16x4 tpack(f32x4 c) {
    uint2 p;
    p.x = pkrtz(tanh_s(c[0]), tanh_s(c[1]));
    p.y = pkrtz(tanh_s(c[2]), tanh_s(c[3]));
    return __builtin_bit_cast(f16x4, p);
}

__global__ __launch_bounds__(256) void prep_kernel(
    const float* __restrict__ W1, const float* __restrict__ b1,
    const float* __restrict__ W2, const float* __restrict__ b2,
    const float* __restrict__ W3, const float* __restrict__ b3,
    const float* __restrict__ Wout, float* __restrict__ ws)
{
    const int tid = blockIdx.x * 256 + threadIdx.x;   // grid 25*256 = 6400
    if (tid < 5632) {                                 // 4 copies * 22 units * 64
        const int cpy = tid / 1408;
        const int r   = tid - cpy * 1408;
        const int u   = r >> 6, lane = r & 63;
        const int q = lane >> 4, l15 = lane & 15;
        float x[8];
        bool lo = false;
        #pragma unroll
        for (int e = 0; e < 8; ++e) {
            const int half = e >> 2, j = e & 3;
            float v;
            if (u < 2) {                       // W1: kt=0; frags mt = u*2+half
                const int mt = u * 2 + half;
                const int k = q * 4 + j;
                v = (k < 7) ? W1[k * 64 + mt * 16 + l15] * SCALE : 0.f;
            } else if (u < 10) {               // W2
                const int idx = u - 2, mt = idx >> 1, kp = idx & 1;
                const int k = (kp * 2 + half) * 16 + q * 4 + j;
                v = W2[k * 64 + mt * 16 + l15] * SCALE;
            } else if (u < 18) {               // W3
                const int idx = u - 10, mt = idx >> 1, kp = idx & 1;
                const int k = (kp * 2 + half) * 16 + q * 4 + j;
                v = W3[k * 64 + mt * 16 + l15] * SCALE;
            } else {                           // Wout hi (18,19) / lo (20,21)
                const int kp = (u - 18) & 1;
                const int k = (kp * 2 + half) * 16 + q * 4 + j;
                v = (l15 < 3) ? Wout[k * 3 + l15] : 0.f;
                lo = (u >= 20);
            }
            x[e] = v;
        }
        u16 outw[8];
        #pragma unroll
        for (int e = 0; e < 8; ++e) {
            const f16 h = (f16)x[e];
            const f16 val = lo ? (f16)(x[e] - (float)h) : h;
            outw[e] = __builtin_bit_cast(u16, val);
        }
        uint4 g;
        g.x = outw[0] | ((u32)outw[1] << 16);
        g.y = outw[2] | ((u32)outw[3] << 16);
        g.z = outw[4] | ((u32)outw[5] << 16);
        g.w = outw[6] | ((u32)outw[7] << 16);
        *(uint4*)((char*)ws + (size_t)cpy * CPY_F * 4 + (size_t)(u * 64 + lane) * 16) = g;
    } else {                                   // biases: 4 copies * 192
        const int b = tid - 5632;
        const int cpy = b / 192, i = b - cpy * 192;
        const int Lb = i >> 6, j = i & 63;
        float bv;
        if (Lb == 0)      bv = b1[j];
        else if (Lb == 1) bv = b2[j];
        else              bv = b3[j];
        ws[cpy * CPY_F + 5632 + i] = bv * SCALE;
    }
}

__global__ __launch_bounds__(BLK, 2) void globe_mfma(
    const float* __restrict__ pts, const float* __restrict__ ctr,
    const float* __restrict__ nrm, const float* __restrict__ areas,
    const float* __restrict__ rlen, const float* __restrict__ bout,
    const float* __restrict__ p_scale, const float* __restrict__ p_bias,
    const float* __restrict__ v_scale, const float* __restrict__ v_bias,
    const float* __restrict__ ws,
    float* __restrict__ out)
{
    __shared__ __align__(16) u16 featL[2][64][8];    // feature rows, 16 B/pair
    __shared__ __align__(16) uint4 geomL[2][64];     // packed geometry
    __shared__ float xr[4];

    const int tid  = threadIdx.x;
    const int lane = tid & 63;
    const int wv   = tid >> 6;
    const int l15  = lane & 15;
    const int q    = lane >> 4;
    const int qf   = q & 1;                          // clamped feature octet
    const int t    = blockIdx.x;                     // both waves: same target

    const float px = pts[3 * t + 0], py = pts[3 * t + 1], pz = pts[3 * t + 2];
    const float invL0 = __builtin_amdgcn_rcpf(rlen[0]);
    const float invL1 = __builtin_amdgcn_rcpf(rlen[1]);
    f32x4 co_init = (f32x4){0.f, 0.f, 0.f, 0.f};
    if (q == 0) { co_init[0] = bout[0]; co_init[1] = bout[1]; co_init[2] = bout[2]; }

    u16 (*ft)[8] = featL[wv];
    uint4* gp = geomL[wv];
    const f16x4 bz = (f16x4){0, 0, 0, 0};
    float accp = 0.f, avx = 0.f, avy = 0.f, avz = 0.f;

    #pragma unroll 1
    for (int ch = 0; ch < 4; ++ch) {
        // chunk-dependent weight copy: defeats LICM hoisting of frag loads
        const uint4* __restrict__ wsU = (const uint4*)ws + ch * CPY_U;
        const float* __restrict__ wsBias = ws + ch * CPY_F + 5632;

        // ==== PREFETCH: L1 frags + L2 frags + L1/L2 biases (covered by the
        //      feature computation below) ====
        const uint4 g0 = wsU[0 * 64 + lane];
        const uint4 g1 = wsU[1 * 64 + lane];
        uint4 w2g[8];
        #pragma unroll
        for (int fi = 0; fi < 8; ++fi) w2g[fi] = wsU[(2 + fi) * 64 + lane];
        float4 bv1[4], bv2[4];
        #pragma unroll
        for (int mt = 0; mt < 4; ++mt) {
            bv1[mt] = *(const float4*)(wsBias + 0 * 64 + mt * 16 + q * 4);
            bv2[mt] = *(const float4*)(wsBias + 1 * 64 + mt * 16 + q * 4);
        }

        const int s = (wv * 4 + ch) * 64 + lane;
        // ---- per-pair geometry + features (lane = pair) ----
        const float cx = ctr[3 * s + 0], cy = ctr[3 * s + 1], cz = ctr[3 * s + 2];
        const float snx = nrm[3 * s + 0], sny = nrm[3 * s + 1], snz = nrm[3 * s + 2];
        const float ar = areas[s];
        const float rvx = px - cx, rvy = py - cy, rvz = pz - cz;
        const float r2 = rvx * rvx + rvy * rvy + rvz * rvz;
        const float r2e = r2 + 1e-8f;
        const float rinv = __builtin_amdgcn_rsqf(r2e);
        const float r = r2e * rinv;
        const float rhx = rvx * rinv, rhy = rvy * rinv, rhz = rvz * rinv;
        const float cth = rhx * snx + rhy * sny + rhz * snz;
        const float c2 = cth * cth;
        const float decay = ar * __builtin_amdgcn_rcpf(r2 + 1.0f);
        {
            uint4 fw;
            fw.x = pkrtz(__builtin_amdgcn_rcpf(fmaf(r, invL0, 1.0f)),
                         __builtin_amdgcn_rcpf(fmaf(r, invL1, 1.0f)));
            fw.y = pkrtz(1.0f, cth);
            fw.z = pkrtz(fmaf(1.5f, c2, -0.5f), cth * fmaf(2.5f, c2, -1.5f));
            fw.w = pkrtz(__logf(ar), 0.0f);
            *(uint4*)&ft[lane][0] = fw;
        }
        {
            uint4 g;
            g.x = __builtin_bit_cast(u32, decay);
            g.y = pkrtz(rhx, rhy);
            g.z = pkrtz(rhz, snx);
            g.w = pkrtz(sny, snz);
            gp[lane] = g;
        }

        // ---- layer 1: features (LDS) -> B2 (registers) ----
        f16x4 B2[4][4];   // [kt][n4]
        {
            f16x4 a1[4];
            a1[0] = lo4(g0); a1[1] = hi4(g0); a1[2] = lo4(g1); a1[3] = hi4(g1);
            #pragma unroll
            for (int n4 = 0; n4 < 4; ++n4) {
                const f16x4 lv = *(const f16x4*)&ft[n4 * 16 + l15][qf * 4];
                const f16x4 bf = (q < 2) ? lv : bz;   // feature k: octets 0,1 only
                f32x4 c[4];
                #pragma unroll
                for (int mt = 0; mt < 4; ++mt) {
                    c[mt] = (f32x4){bv1[mt].x, bv1[mt].y, bv1[mt].z, bv1[mt].w};
                    c[mt] = mfma16(a1[mt], bf, c[mt]);
                }
                #pragma unroll
                for (int mt = 0; mt < 4; ++mt)
                    B2[mt][n4] = tpack(c[mt]);        // C tile == next B frag
            }
        }

        // ==== PREFETCH: L3 frags + L3 bias (covered by layer-2 compute) ====
        uint4 w3g[8];
        #pragma unroll
        for (int fi = 0; fi < 8; ++fi) w3g[fi] = wsU[(10 + fi) * 64 + lane];
        float4 bv3[4];
        #pragma unroll
        for (int mt = 0; mt < 4; ++mt)
            bv3[mt] = *(const float4*)(wsBias + 2 * 64 + mt * 16 + q * 4);

        // ---- layer 2: B2 -> B3 (pure register dataflow) ----
        f16x4 B3[4][4];
        {
            f16x4 a[4][4];
            #pragma unroll
            for (int mt = 0; mt < 4; ++mt) {
                a[mt][0] = lo4(w2g[2 * mt]);     a[mt][1] = hi4(w2g[2 * mt]);
                a[mt][2] = lo4(w2g[2 * mt + 1]); a[mt][3] = hi4(w2g[2 * mt + 1]);
            }
            #pragma unroll
            for (int n4 = 0; n4 < 4; ++n4) {
                f32x4 c[4];
                #pragma unroll
                for (int mt = 0; mt < 4; ++mt)
                    c[mt] = (f32x4){bv2[mt].x, bv2[mt].y, bv2[mt].z, bv2[mt].w};
                #pragma unroll
                for (int kt = 0; kt < 4; ++kt)
                    #pragma unroll
                    for (int mt = 0; mt < 4; ++mt)
                        c[mt] = mfma16(a[mt][kt], B2[kt][n4], c[mt]);
                #pragma unroll
                for (int mt = 0; mt < 4; ++mt)
                    B3[mt][n4] = tpack(c[mt]);
            }
        }

        // ==== PREFETCH: Wout frags (covered by layer-3 compute) ====
        uint4 wog[4];
        #pragma unroll
        for (int fi = 0; fi < 4; ++fi) wog[fi] = wsU[(18 + fi) * 64 + lane];

        // ---- layer 3: B3 -> BO ----
        f16x4 BO[4][4];
        {
            f16x4 a[4][4];
            #pragma unroll
            for (int mt = 0; mt < 4; ++mt) {
                a[mt][0] = lo4(w3g[2 * mt]);     a[mt][1] = hi4(w3g[2 * mt]);
                a[mt][2] = lo4(w3g[2 * mt + 1]); a[mt][3] = hi4(w3g[2 * mt + 1]);
            }
            #pragma unroll
            for (int n4 = 0; n4 < 4; ++n4) {
                f32x4 c[4];
                #pragma unroll
                for (int mt = 0; mt < 4; ++mt)
                    c[mt] = (f32x4){bv3[mt].x, bv3[mt].y, bv3[mt].z, bv3[mt].w};
                #pragma unroll
                for (int kt = 0; kt < 4; ++kt)
                    #pragma unroll
                    for (int mt = 0; mt < 4; ++mt)
                        c[mt] = mfma16(a[mt][kt], B3[kt][n4], c[mt]);
                #pragma unroll
                for (int mt = 0; mt < 4; ++mt)
                    BO[mt][n4] = tpack(c[mt]);
            }
        }

        // ---- output layer (Wout hi/lo) + decay-weighted accumulation ----
        {
            f16x4 aoh[4], aol[4];
            aoh[0] = lo4(wog[0]); aoh[1] = hi4(wog[0]);
            aoh[2] = lo4(wog[1]); aoh[3] = hi4(wog[1]);
            aol[0] = lo4(wog[2]); aol[1] = hi4(wog[2]);
            aol[2] = lo4(wog[3]); aol[3] = hi4(wog[3]);
            #pragma unroll
            for (int n4 = 0; n4 < 4; ++n4) {
                f32x4 co = co_init;
                #pragma unroll
                for (int kt = 0; kt < 4; ++kt) {
                    co = mfma16(aoh[kt], BO[kt][n4], co);
                    co = mfma16(aol[kt], BO[kt][n4], co);
                }
                if (q == 0) {   // C rows 0..2 = out channels, lanes 0..15
                    const uint4 g = gp[n4 * 16 + l15];
                    const float d = __builtin_bit_cast(float, g.x);
                    const float2 rxy = __half22float2(__builtin_bit_cast(__half2, g.y));
                    const float2 rzx = __half22float2(__builtin_bit_cast(__half2, g.z));
                    const float2 nyz = __half22float2(__builtin_bit_cast(__half2, g.w));
                    const float o0 = co[0], o1 = co[1], o2 = co[2];
                    accp = fmaf(o0, d, accp);
                    avx  = fmaf(fmaf(o1, rxy.x, o2 * rzx.y), d, avx);
                    avy  = fmaf(fmaf(o1, rxy.y, o2 * nyz.x), d, avy);
                    avz  = fmaf(fmaf(o1, rzx.x, o2 * nyz.y), d, avz);
                }
            }
        }
    }

    // ---- reduce across the 16 accumulating lanes ----
    #pragma unroll
    for (int off = 8; off > 0; off >>= 1) {
        accp += __shfl_down(accp, off);
        avx  += __shfl_down(avx,  off);
        avy  += __shfl_down(avy,  off);
        avz  += __shfl_down(avz,  off);
    }

    // ---- cross-wave combine ----
    if (wv == 1 && lane == 0) {
        xr[0] = accp; xr[1] = avx; xr[2] = avy; xr[3] = avz;
    }
    __syncthreads();
    if (wv == 0 && lane == 0) {
        accp += xr[0]; avx += xr[1]; avy += xr[2]; avz += xr[3];
        const float ps = p_scale[0], pb = p_bias[0];
        const float vs = v_scale[0], vb = v_bias[0];
        out[4 * t + 0] = fmaf(accp, ps, pb);
        out[4 * t + 1] = fmaf(avx, vs, vb);
        out[4 * t + 2] = fmaf(avy, vs, vb);
        out[4 * t + 3] = fmaf(avz, vs, vb);
    }
}

extern "C" void kernel_launch(void* const* d_in, const int* in_sizes, int n_in,
                              void* d_out, int out_size, void* d_ws, size_t ws_size,
                              hipStream_t stream) {
    (void)in_sizes; (void)n_in; (void)ws_size; (void)out_size;
    const float* pts   = (const float*)d_in[0];
    const float* ctr   = (const float*)d_in[1];
    const float* nrm   = (const float*)d_in[2];
    const float* areas = (const float*)d_in[3];
    const float* rlen  = (const float*)d_in[4];
    const float* W1    = (const float*)d_in[5];
    const float* b1    = (const float*)d_in[6];
    const float* W2    = (const float*)d_in[7];
    const float* b2    = (const float*)d_in[8];
    const float* W3    = (const float*)d_in[9];
    const float* b3    = (const float*)d_in[10];
    const float* Wout  = (const float*)d_in[11];
    const float* bout  = (const float*)d_in[12];
    const float* ps    = (const float*)d_in[13];
    const float* pb    = (const float*)d_in[14];
    const float* vs    = (const float*)d_in[15];
    const float* vb    = (const float*)d_in[16];
    float* ws = (float*)d_ws;

    prep_kernel<<<25, 256, 0, stream>>>(W1, b1, W2, b2, W3, b3, Wout, ws);
    globe_mfma<<<N_T, BLK, 0, stream>>>(
        pts, ctr, nrm, areas, rlen, bout, ps, pb, vs, vb, ws, (float*)d_out);
}

// Round 16
// 143.495 us; speedup vs baseline: 1.0850x; 1.0850x over previous
//
#include <hip/hip_runtime.h>
#include <hip/hip_fp16.h>

// GLOBE_61864708931733 — R16: dual-stream ILP (2 chunks in lockstep per wave).
// R15 post-mortem: prefetch neutral. Six structures all 68-75us at VALUBusy
// 52-60% -> VALU+trans issue ~93k cy/SIMD is the big pipe; ~45% idle is
// IN-WAVE dependency stalls between MFMA-phase and tanh-phase of consecutive
// layers (waves/prefetch didn't help; only in-wave ILP can cover it at ~2
// effective waves/SIMD). R16: two independent MLP streams interleaved per
// wave; A-frags/biases shared (halves weight-load instructions per chunk).
// Structure otherwise = R14 (16x16x16 C==B register dataflow, proven
// absmax 0.25). (128,2) bounds; est ~150 VGPR.

#define N_T 2048
#define N_S 512
#define BLK 128
#define SCALE 2.885390081777927f   // 2*log2(e)

// d_ws: 4 copies, stride 5888 floats (23552 B):
//   units 0..21: f16x4-frag pairs, unit u = [64 lanes][16 B]
//     u 0..1:  W1 (unit0: mt0 lo / mt1 hi; unit1: mt2/mt3), kt=0 only
//     u 2..9:  W2: unit 2+mt*2+kp = frags (mt, kt=2kp) lo / (mt, 2kp+1) hi
//     u 10..17: W3 same
//     u 18..19: Wout hi | u 20..21: Wout lo
//   floats 5632..5823: scaled biases [3][64]
#define CPY_F 5888     // floats per copy
#define CPY_U 1472     // 16B units per copy

typedef _Float16 f16;
typedef _Float16 f16x4 __attribute__((ext_vector_type(4)));
typedef float f32x4 __attribute__((ext_vector_type(4)));
typedef unsigned short u16;
typedef unsigned int u32;

__device__ __forceinline__ float tanh_s(float x) {
    // x is already SCALE*y; tanh(y) = 1 - 2/(exp2(x)+1). Saturates exactly.
    float e = __builtin_amdgcn_exp2f(x);
    return fmaf(-2.0f, __builtin_amdgcn_rcpf(e + 1.0f), 1.0f);
}

__device__ __forceinline__ f32x4 mfma16(f16x4 a, f16x4 b, f32x4 c) {
    return __builtin_amdgcn_mfma_f32_16x16x16f16(a, b, c, 0, 0, 0);
}

__device__ __forceinline__ u32 pkrtz(float a, float b) {
    return __builtin_bit_cast(u32, __builtin_amdgcn_cvt_pkrtz(a, b));
}

__device__ __forceinline__ f16x4 lo4(uint4 g) {
    uint2 p; p.x = g.x; p.y = g.y;
    return __builtin_bit_cast(f16x4, p);
}
__device__ __forceinline__ f16x4 hi4(uint4 g) {
    uint2 p; p.x = g.z; p.y = g.w;
    return __builtin_bit_cast(f16x4, p);
}

// tanh + pack a C f32x4 into the next layer's B frag (C==B layout identity).
__device__ __forceinline__ f16x4 tpack(f32x4 c) {
    uint2 p;
    p.x = pkrtz(tanh_s(c[0]), tanh_s(c[1]));
    p.y = pkrtz(tanh_s(c[2]), tanh_s(c[3]));
    return __builtin_bit_cast(f16x4, p);
}

__global__ __launch_bounds__(256) void prep_kernel(
    const float* __restrict__ W1, const float* __restrict__ b1,
    const float* __restrict__ W2, const float* __restrict__ b2,
    const float* __restrict__ W3, const float* __restrict__ b3,
    const float* __restrict__ Wout, float* __restrict__ ws)
{
    const int tid = blockIdx.x * 256 + threadIdx.x;   // grid 25*256 = 6400
    if (tid < 5632) {                                 // 4 copies * 22 units * 64
        const int cpy = tid / 1408;
        const int r   = tid - cpy * 1408;
        const int u   = r >> 6, lane = r & 63;
        const int q = lane >> 4, l15 = lane & 15;
        float x[8];
        bool lo = false;
        #pragma unroll
        for (int e = 0; e < 8; ++e) {
            const int half = e >> 2, j = e & 3;
            float v;
            if (u < 2) {                       // W1: kt=0; frags mt = u*2+half
                const int mt = u * 2 + half;
                const int k = q * 4 + j;
                v = (k < 7) ? W1[k * 64 + mt * 16 + l15] * SCALE : 0.f;
            } else if (u < 10) {               // W2
                const int idx = u - 2, mt = idx >> 1, kp = idx & 1;
                const int k = (kp * 2 + half) * 16 + q * 4 + j;
                v = W2[k * 64 + mt * 16 + l15] * SCALE;
            } else if (u < 18) {               // W3
                const int idx = u - 10, mt = idx >> 1, kp = idx & 1;
                const int k = (kp * 2 + half) * 16 + q * 4 + j;
                v = W3[k * 64 + mt * 16 + l15] * SCALE;
            } else {                           // Wout hi (18,19) / lo (20,21)
                const int kp = (u - 18) & 1;
                const int k = (kp * 2 + half) * 16 + q * 4 + j;
                v = (l15 < 3) ? Wout[k * 3 + l15] : 0.f;
                lo = (u >= 20);
            }
            x[e] = v;
        }
        u16 outw[8];
        #pragma unroll
        for (int e = 0; e < 8; ++e) {
            const f16 h = (f16)x[e];
            const f16 val = lo ? (f16)(x[e] - (float)h) : h;
            outw[e] = __builtin_bit_cast(u16, val);
        }
        uint4 g;
        g.x = outw[0] | ((u32)outw[1] << 16);
        g.y = outw[2] | ((u32)outw[3] << 16);
        g.z = outw[4] | ((u32)outw[5] << 16);
        g.w = outw[6] | ((u32)outw[7] << 16);
        *(uint4*)((char*)ws + (size_t)cpy * CPY_F * 4 + (size_t)(u * 64 + lane) * 16) = g;
    } else {                                   // biases: 4 copies * 192
        const int b = tid - 5632;
        const int cpy = b / 192, i = b - cpy * 192;
        const int Lb = i >> 6, j = i & 63;
        float bv;
        if (Lb == 0)      bv = b1[j];
        else if (Lb == 1) bv = b2[j];
        else              bv = b3[j];
        ws[cpy * CPY_F + 5632 + i] = bv * SCALE;
    }
}

__global__ __launch_bounds__(BLK, 2) void globe_mfma(
    const float* __restrict__ pts, const float* __restrict__ ctr,
    const float* __restrict__ nrm, const float* __restrict__ areas,
    const float* __restrict__ rlen, const float* __restrict__ bout,
    const float* __restrict__ p_scale, const float* __restrict__ p_bias,
    const float* __restrict__ v_scale, const float* __restrict__ v_bias,
    const float* __restrict__ ws,
    float* __restrict__ out)
{
    __shared__ __align__(16) u16 featL[2][2][64][8];   // [wave][stream]
    __shared__ __align__(16) uint4 geomL[2][2][64];
    __shared__ float xr[4];

    const int tid  = threadIdx.x;
    const int lane = tid & 63;
    const int wv   = tid >> 6;
    const int l15  = lane & 15;
    const int q    = lane >> 4;
    const int qf   = q & 1;                          // clamped feature octet
    const int t    = blockIdx.x;                     // both waves: same target

    const float px = pts[3 * t + 0], py = pts[3 * t + 1], pz = pts[3 * t + 2];
    const float invL0 = __builtin_amdgcn_rcpf(rlen[0]);
    const float invL1 = __builtin_amdgcn_rcpf(rlen[1]);
    f32x4 co_init = (f32x4){0.f, 0.f, 0.f, 0.f};
    if (q == 0) { co_init[0] = bout[0]; co_init[1] = bout[1]; co_init[2] = bout[2]; }

    const f16x4 bz = (f16x4){0, 0, 0, 0};
    float accp = 0.f, avx = 0.f, avy = 0.f, avz = 0.f;

    #pragma unroll 1
    for (int ch = 0; ch < 2; ++ch) {
        // chunk-dependent weight copy (copies 0,2 used): defeats LICM
        const uint4* __restrict__ wsU = (const uint4*)ws + (ch * 2) * CPY_U;
        const float* __restrict__ wsBias = ws + (ch * 2) * CPY_F + 5632;

        // ---- features + geometry for BOTH streams ----
        #pragma unroll
        for (int st = 0; st < 2; ++st) {
            const int s = (wv * 4 + ch * 2 + st) * 64 + lane;
            const float cx = ctr[3 * s + 0], cy = ctr[3 * s + 1], cz = ctr[3 * s + 2];
            const float snx = nrm[3 * s + 0], sny = nrm[3 * s + 1], snz = nrm[3 * s + 2];
            const float ar = areas[s];
            const float rvx = px - cx, rvy = py - cy, rvz = pz - cz;
            const float r2 = rvx * rvx + rvy * rvy + rvz * rvz;
            const float r2e = r2 + 1e-8f;
            const float rinv = __builtin_amdgcn_rsqf(r2e);
            const float r = r2e * rinv;
            const float rhx = rvx * rinv, rhy = rvy * rinv, rhz = rvz * rinv;
            const float cth = rhx * snx + rhy * sny + rhz * snz;
            const float c2 = cth * cth;
            const float decay = ar * __builtin_amdgcn_rcpf(r2 + 1.0f);
            uint4 fw;
            fw.x = pkrtz(__builtin_amdgcn_rcpf(fmaf(r, invL0, 1.0f)),
                         __builtin_amdgcn_rcpf(fmaf(r, invL1, 1.0f)));
            fw.y = pkrtz(1.0f, cth);
            fw.z = pkrtz(fmaf(1.5f, c2, -0.5f), cth * fmaf(2.5f, c2, -1.5f));
            fw.w = pkrtz(__logf(ar), 0.0f);
            *(uint4*)&featL[wv][st][lane][0] = fw;
            uint4 g;
            g.x = __builtin_bit_cast(u32, decay);
            g.y = pkrtz(rhx, rhy);
            g.z = pkrtz(rhz, snx);
            g.w = pkrtz(sny, snz);
            geomL[wv][st][lane] = g;
        }

        // ---- layer 1 (shared frags, both streams) ----
        f16x4 B2[2][4][4];   // [stream][kt][n4]
        {
            const uint4 g0 = wsU[0 * 64 + lane], g1 = wsU[1 * 64 + lane];
            f16x4 a1[4];
            a1[0] = lo4(g0); a1[1] = hi4(g0); a1[2] = lo4(g1); a1[3] = hi4(g1);
            float4 bv[4];
            #pragma unroll
            for (int mt = 0; mt < 4; ++mt)
                bv[mt] = *(const float4*)(wsBias + 0 * 64 + mt * 16 + q * 4);
            #pragma unroll
            for (int n4 = 0; n4 < 4; ++n4) {
                f16x4 bf[2];
                #pragma unroll
                for (int st = 0; st < 2; ++st) {
                    const f16x4 lv = *(const f16x4*)&featL[wv][st][n4 * 16 + l15][qf * 4];
                    bf[st] = (q < 2) ? lv : bz;
                }
                f32x4 c[2][4];
                #pragma unroll
                for (int mt = 0; mt < 4; ++mt) {
                    c[0][mt] = (f32x4){bv[mt].x, bv[mt].y, bv[mt].z, bv[mt].w};
                    c[1][mt] = c[0][mt];
                    c[0][mt] = mfma16(a1[mt], bf[0], c[0][mt]);
                    c[1][mt] = mfma16(a1[mt], bf[1], c[1][mt]);
                }
                #pragma unroll
                for (int mt = 0; mt < 4; ++mt) {
                    B2[0][mt][n4] = tpack(c[0][mt]);
                    B2[1][mt][n4] = tpack(c[1][mt]);
                }
            }
        }

        // ---- layer 2 ----
        f16x4 B3[2][4][4];
        {
            f16x4 a[4][4];
            #pragma unroll
            for (int mt = 0; mt < 4; ++mt) {
                const uint4 ga = wsU[(2 + 2 * mt) * 64 + lane];
                const uint4 gb = wsU[(3 + 2 * mt) * 64 + lane];
                a[mt][0] = lo4(ga); a[mt][1] = hi4(ga);
                a[mt][2] = lo4(gb); a[mt][3] = hi4(gb);
            }
            float4 bv[4];
            #pragma unroll
            for (int mt = 0; mt < 4; ++mt)
                bv[mt] = *(const float4*)(wsBias + 1 * 64 + mt * 16 + q * 4);
            #pragma unroll
            for (int n4 = 0; n4 < 4; ++n4) {
                f32x4 c[2][4];
                #pragma unroll
                for (int mt = 0; mt < 4; ++mt) {
                    c[0][mt] = (f32x4){bv[mt].x, bv[mt].y, bv[mt].z, bv[mt].w};
                    c[1][mt] = c[0][mt];
                }
                #pragma unroll
                for (int kt = 0; kt < 4; ++kt)
                    #pragma unroll
                    for (int mt = 0; mt < 4; ++mt) {
                        c[0][mt] = mfma16(a[mt][kt], B2[0][kt][n4], c[0][mt]);
                        c[1][mt] = mfma16(a[mt][kt], B2[1][kt][n4], c[1][mt]);
                    }
                #pragma unroll
                for (int mt = 0; mt < 4; ++mt) {
                    B3[0][mt][n4] = tpack(c[0][mt]);
                    B3[1][mt][n4] = tpack(c[1][mt]);
                }
            }
        }

        // ---- layer 3 ----
        f16x4 BO[2][4][4];
        {
            f16x4 a[4][4];
            #pragma unroll
            for (int mt = 0; mt < 4; ++mt) {
                const uint4 ga = wsU[(10 + 2 * mt) * 64 + lane];
                const uint4 gb = wsU[(11 + 2 * mt) * 64 + lane];
                a[mt][0] = lo4(ga); a[mt][1] = hi4(ga);
                a[mt][2] = lo4(gb); a[mt][3] = hi4(gb);
            }
            float4 bv[4];
            #pragma unroll
            for (int mt = 0; mt < 4; ++mt)
                bv[mt] = *(const float4*)(wsBias + 2 * 64 + mt * 16 + q * 4);
            #pragma unroll
            for (int n4 = 0; n4 < 4; ++n4) {
                f32x4 c[2][4];
                #pragma unroll
                for (int mt = 0; mt < 4; ++mt) {
                    c[0][mt] = (f32x4){bv[mt].x, bv[mt].y, bv[mt].z, bv[mt].w};
                    c[1][mt] = c[0][mt];
                }
                #pragma unroll
                for (int kt = 0; kt < 4; ++kt)
                    #pragma unroll
                    for (int mt = 0; mt < 4; ++mt) {
                        c[0][mt] = mfma16(a[mt][kt], B3[0][kt][n4], c[0][mt]);
                        c[1][mt] = mfma16(a[mt][kt], B3[1][kt][n4], c[1][mt]);
                    }
                #pragma unroll
                for (int mt = 0; mt < 4; ++mt) {
                    BO[0][mt][n4] = tpack(c[0][mt]);
                    BO[1][mt][n4] = tpack(c[1][mt]);
                }
            }
        }

        // ---- output layer + decay-weighted accumulation (both streams) ----
        {
            const uint4 gh0 = wsU[18 * 64 + lane], gh1 = wsU[19 * 64 + lane];
            const uint4 gl0 = wsU[20 * 64 + lane], gl1 = wsU[21 * 64 + lane];
            f16x4 aoh[4], aol[4];
            aoh[0] = lo4(gh0); aoh[1] = hi4(gh0); aoh[2] = lo4(gh1); aoh[3] = hi4(gh1);
            aol[0] = lo4(gl0); aol[1] = hi4(gl0); aol[2] = lo4(gl1); aol[3] = hi4(gl1);
            #pragma unroll
            for (int n4 = 0; n4 < 4; ++n4) {
                f32x4 co[2];
                co[0] = co_init; co[1] = co_init;
                #pragma unroll
                for (int kt = 0; kt < 4; ++kt) {
                    co[0] = mfma16(aoh[kt], BO[0][kt][n4], co[0]);
                    co[1] = mfma16(aoh[kt], BO[1][kt][n4], co[1]);
                    co[0] = mfma16(aol[kt], BO[0][kt][n4], co[0]);
                    co[1] = mfma16(aol[kt], BO[1][kt][n4], co[1]);
                }
                if (q == 0) {
                    #pragma unroll
                    for (int st = 0; st < 2; ++st) {
                        const uint4 g = geomL[wv][st][n4 * 16 + l15];
                        const float d = __builtin_bit_cast(float, g.x);
                        const float2 rxy = __half22float2(__builtin_bit_cast(__half2, g.y));
                        const float2 rzx = __half22float2(__builtin_bit_cast(__half2, g.z));
                        const float2 nyz = __half22float2(__builtin_bit_cast(__half2, g.w));
                        const float o0 = co[st][0], o1 = co[st][1], o2 = co[st][2];
                        accp = fmaf(o0, d, accp);
                        avx  = fmaf(fmaf(o1, rxy.x, o2 * rzx.y), d, avx);
                        avy  = fmaf(fmaf(o1, rxy.y, o2 * nyz.x), d, avy);
                        avz  = fmaf(fmaf(o1, rzx.x, o2 * nyz.y), d, avz);
                    }
                }
            }
        }
    }

    // ---- reduce across the 16 accumulating lanes ----
    #pragma unroll
    for (int off = 8; off > 0; off >>= 1) {
        accp += __shfl_down(accp, off);
        avx  += __shfl_down(avx,  off);
        avy  += __shfl_down(avy,  off);
        avz  += __shfl_down(avz,  off);
    }

    // ---- cross-wave combine ----
    if (wv == 1 && lane == 0) {
        xr[0] = accp; xr[1] = avx; xr[2] = avy; xr[3] = avz;
    }
    __syncthreads();
    if (wv == 0 && lane == 0) {
        accp += xr[0]; avx += xr[1]; avy += xr[2]; avz += xr[3];
        const float ps = p_scale[0], pb = p_bias[0];
        const float vs = v_scale[0], vb = v_bias[0];
        out[4 * t + 0] = fmaf(accp, ps, pb);
        out[4 * t + 1] = fmaf(avx, vs, vb);
        out[4 * t + 2] = fmaf(avy, vs, vb);
        out[4 * t + 3] = fmaf(avz, vs, vb);
    }
}

extern "C" void kernel_launch(void* const* d_in, const int* in_sizes, int n_in,
                              void* d_out, int out_size, void* d_ws, size_t ws_size,
                              hipStream_t stream) {
    (void)in_sizes; (void)n_in; (void)ws_size; (void)out_size;
    const float* pts   = (const float*)d_in[0];
    const float* ctr   = (const float*)d_in[1];
    const float* nrm   = (const float*)d_in[2];
    const float* areas = (const float*)d_in[3];
    const float* rlen  = (const float*)d_in[4];
    const float* W1    = (const float*)d_in[5];
    const float* b1    = (const float*)d_in[6];
    const float* W2    = (const float*)d_in[7];
    const float* b2    = (const float*)d_in[8];
    const float* W3    = (const float*)d_in[9];
    const float* b3    = (const float*)d_in[10];
    const float* Wout  = (const float*)d_in[11];
    const float* bout  = (const float*)d_in[12];
    const float* ps    = (const float*)d_in[13];
    const float* pb    = (const float*)d_in[14];
    const float* vs    = (const float*)d_in[15];
    const float* vb    = (const float*)d_in[16];
    float* ws = (float*)d_ws;

    prep_kernel<<<25, 256, 0, stream>>>(W1, b1, W2, b2, W3, b3, Wout, ws);
    globe_mfma<<<N_T, BLK, 0, stream>>>(
        pts, ctr, nrm, areas, rlen, bout, ps, pb, vs, vb, ws, (float*)d_out);
}